// Round 1
// 209.492 us; speedup vs baseline: 1.0192x; 1.0192x over previous
//
#include <hip/hip_runtime.h>
#include <hip/hip_bf16.h>
#include <math.h>

#define N 20000
#define E 160000
#define MUL 64
#define EDIM 8
#define NZ 4

#define INV_SQRT_MUL 0.125f
#define INV_E 0.35355339059327373f
#define INV_N 0.35355339059327373f
#define INV2 0.08838834764831845f
#define INV_SC 0.0625f
#define INV_SQRT3 0.5773502691896258f

typedef unsigned short u16;
typedef unsigned int u32;
typedef short bf16x8 __attribute__((ext_vector_type(8)));
typedef float f32x4 __attribute__((ext_vector_type(4)));

__device__ __forceinline__ float silu(float v) {
    return v / (1.0f + __expf(-v));
}
__device__ __forceinline__ u16 f2bf(float f) {
    union { float f; unsigned int u; } v; v.f = f;
    unsigned int r = (v.u + 0x7FFFu + ((v.u >> 16) & 1u)) >> 16;
    return (u16)r;
}
__device__ __forceinline__ float bflo(u32 p) {
    union { unsigned int u; float f; } v; v.u = p << 16; return v.f;
}
__device__ __forceinline__ float bfhi(u32 p) {
    union { unsigned int u; float f; } v; v.u = p & 0xFFFF0000u; return v.f;
}
#define MFMA(a, b, c) __builtin_amdgcn_mfma_f32_16x16x32_bf16(a, b, c, 0, 0, 0)

// Layouts:
//  A1  [N][192]:  0..127 gathered s0 (scales folded), 128..191 bf16(x0)
//  A2g [3N][128]: gathered s1 only (xz tail computed on the fly in fused)
//  x1p [3N][64] bf16(x1)
//  Bt1m [128][128]=W20^T; Bt1z [4][128][64]=Wsc0_z^T*INV_SC
//  Bt2 [64][384] (k<128: W21^T; k>=128: Wsc1 flat u*4+z)
//  W0b/W1b [64][64]=lin1^T*INV_SQRT_MUL
//  head[n]: last edge with dst=n (-1 none); nl[e] = {prev edge, src}

// ---------------------------------------------------------------------------
// Front: grid-partitioned [prep | wconv | hid | list-build]
// ---------------------------------------------------------------------------
#define PREP_B  5000
#define WCONV_B 320
#define HID_B   5000
#define LIST_B  625

__global__ __launch_bounds__(256) void k_front(
    const float* __restrict__ x,
    const float* __restrict__ eemb, const int* __restrict__ eidx,
    const float* __restrict__ W20, const float* __restrict__ Wsc0,
    const float* __restrict__ W21, const float* __restrict__ Wsc1,
    const float* __restrict__ W0, const float* __restrict__ W1,
    const float* __restrict__ Wm1,
    u16* __restrict__ A1, u16* __restrict__ x1p,
    u16* __restrict__ Bt1m, u16* __restrict__ Bt1z, u16* __restrict__ Bt2,
    u16* __restrict__ W0b, u16* __restrict__ W1b,
    float* __restrict__ hid, int* __restrict__ head, int2* __restrict__ nl)
{
    const int b = blockIdx.x;
    const int tid = threadIdx.x;
    __shared__ float xr[4][256];

    if (b < PREP_B) {
        const int n0 = b * 4;
        #pragma unroll
        for (int t = 0; t < 4; ++t)
            xr[t][tid] = x[(size_t)(n0 + t) * 256 + tid];
        __syncthreads();
        #pragma unroll
        for (int t = 0; t < 4; ++t) {
            const int n = n0 + t;
            if (tid < 64) {
                A1[(size_t)n * 192 + 128 + tid] = f2bf(xr[t][tid]);
            } else {
                int q = tid - 64;
                int d = q >> 6, uu = q & 63;
                x1p[((size_t)n * 3 + d) * 64 + uu] = f2bf(xr[t][64 + uu * 3 + d]);
            }
        }
    } else if (b < PREP_B + WCONV_B) {
        int i = (b - PREP_B) * 256 + tid;
        if (i < 16384) {
            int w = i >> 7, k = i & 127;
            Bt1m[i] = f2bf(W20[k * 128 + w]);
        } else if (i < 49152) {
            int j = i - 16384;
            int z = j >> 13, r = j & 8191, w = r >> 6, k = r & 63;
            Bt1z[j] = f2bf(Wsc0[(k * 4 + z) * 128 + w] * INV_SC);
        } else if (i < 73728) {
            int j = i - 49152;
            int w = j / 384, k = j % 384;
            float v = (k < 128) ? W21[k * 64 + w] : Wsc1[(k - 128) * 64 + w];
            Bt2[j] = f2bf(v);
        } else if (i < 77824) {
            int j = i - 73728;
            int v = j >> 6, u = j & 63;
            W0b[j] = f2bf(W0[u * 64 + v] * INV_SQRT_MUL);
        } else {
            int j = i - 77824;
            int v = j >> 6, u = j & 63;
            W1b[j] = f2bf(W1[u * 64 + v] * INV_SQRT_MUL);
        }
    } else if (b < PREP_B + WCONV_B + HID_B) {
        int i = (b - PREP_B - WCONV_B) * 256 + tid;
        int e = i >> 3, k = i & 7;
        float s = 0.f;
        #pragma unroll
        for (int j = 0; j < 8; ++j)
            s += eemb[(size_t)e * 8 + j] * Wm1[j * 8 + k];
        hid[i] = silu(s * INV_E);
    } else {
        int e = (b - PREP_B - WCONV_B - HID_B) * 256 + tid;
        if (e < E) {
            int src = eidx[e];
            int dst = eidx[E + e];
            int old = atomicExch(&head[dst], e);
            nl[e] = make_int2(old, src);
        }
    }
}

// ---------------------------------------------------------------------------
// h-GEMM: lin1 MFMA -> hc bf16 AoS (hc[n][v][4] = g0,g1x,g1y,g1z)
// ---------------------------------------------------------------------------
__global__ __launch_bounds__(256) void k_hgemm(
    const u16* __restrict__ A1, const u16* __restrict__ x1p,
    const u16* __restrict__ W0b, const u16* __restrict__ W1b,
    u16* __restrict__ hc)
{
    const int lane = threadIdx.x & 63;
    const int g = blockIdx.x * 4 + (threadIdx.x >> 6);
    const int quad = lane >> 4, l16 = lane & 15;
    const bool isC1 = (g >= 1250);
    const int row0 = isC1 ? (g - 1250) * 16 : g * 16;
    const u16* Ap = isC1 ? (x1p + (size_t)(row0 + l16) * 64)
                         : (A1 + (size_t)(row0 + l16) * 192 + 128);
    const u16* Bp = isC1 ? W1b : W0b;

    f32x4 acc[4] = {};
    #pragma unroll
    for (int k0 = 0; k0 < 64; k0 += 32) {
        bf16x8 a = *(const bf16x8*)(Ap + k0 + quad * 8);
        #pragma unroll
        for (int ct = 0; ct < 4; ++ct) {
            bf16x8 bb = *(const bf16x8*)(Bp + (size_t)(ct * 16 + l16) * 64 + k0 + quad * 8);
            acc[ct] = MFMA(a, bb, acc[ct]);
        }
    }
    #pragma unroll
    for (int ct = 0; ct < 4; ++ct) {
        #pragma unroll
        for (int r = 0; r < 4; ++r) {
            int row = row0 + quad * 4 + r;
            int vv = ct * 16 + l16;
            if (!isC1) {
                hc[(size_t)row * 256 + vv * 4] = f2bf(acc[ct][r]);
            } else {
                int n = row / 3, d = row - 3 * (row / 3);
                hc[(size_t)n * 256 + vv * 4 + 1 + d] = f2bf(acc[ct][r]);
            }
        }
    }
}

// ---------------------------------------------------------------------------
// Gather v7: one wave per dst node; linked-list chase with depth-2 pipeline
// (next payload + next-next nl issued every iteration).
// ---------------------------------------------------------------------------
__global__ __launch_bounds__(256) void k_gather(
    const int* __restrict__ head, const int2* __restrict__ nl,
    const float* __restrict__ eattr, const float* __restrict__ hid,
    const u32* __restrict__ hc2, const float* __restrict__ Wm2,
    u16* __restrict__ A1, u16* __restrict__ A2g)
{
    const int lane = threadIdx.x & 63;
    const int n = blockIdx.x * 4 + (threadIdx.x >> 6);

    float wm0[8], wm1[8], wm2r[8], wm3[8];
    #pragma unroll
    for (int k = 0; k < 8; ++k) {
        wm0[k]  = Wm2[k * 256 + lane];
        wm1[k]  = Wm2[k * 256 + 64 + lane];
        wm2r[k] = Wm2[k * 256 + 128 + lane];
        wm3[k]  = Wm2[k * 256 + 192 + lane];
    }

    float acc0a = 0.f, acc0b = 0.f;
    float s1a[3] = {0.f, 0.f, 0.f}, s1b[3] = {0.f, 0.f, 0.f};

    int e0 = head[n];
    if (e0 != -1) {
        int2 v0 = nl[e0];
        float4 ea = ((const float4*)eattr)[e0];
        float4 hA = ((const float4*)hid)[(size_t)e0 * 2];
        float4 hB = ((const float4*)hid)[(size_t)e0 * 2 + 1];
        uint2  hp = ((const uint2*)hc2)[(size_t)v0.y * 64 + lane];
        int e1 = v0.x;
        int2 v1 = make_int2(-1, 0);
        if (e1 != -1) v1 = nl[e1];

        while (true) {
            int e2 = -1;
            int2 v2 = make_int2(-1, 0);
            float4 eaN, hAN, hBN; uint2 hpN;
            if (e1 != -1) {
                e2 = v1.x;
                if (e2 != -1) v2 = nl[e2];
                eaN = ((const float4*)eattr)[e1];
                hAN = ((const float4*)hid)[(size_t)e1 * 2];
                hBN = ((const float4*)hid)[(size_t)e1 * 2 + 1];
                hpN = ((const uint2*)hc2)[(size_t)v1.y * 64 + lane];
            }

            float w1 = hA.x*wm0[0]+hA.y*wm0[1]+hA.z*wm0[2]+hA.w*wm0[3]
                     + hB.x*wm0[4]+hB.y*wm0[5]+hB.z*wm0[6]+hB.w*wm0[7];
            float w2 = hA.x*wm1[0]+hA.y*wm1[1]+hA.z*wm1[2]+hA.w*wm1[3]
                     + hB.x*wm1[4]+hB.y*wm1[5]+hB.z*wm1[6]+hB.w*wm1[7];
            float w3 = hA.x*wm2r[0]+hA.y*wm2r[1]+hA.z*wm2r[2]+hA.w*wm2r[3]
                     + hB.x*wm2r[4]+hB.y*wm2r[5]+hB.z*wm2r[6]+hB.w*wm2r[7];
            float w4 = hA.x*wm3[0]+hA.y*wm3[1]+hA.z*wm3[2]+hA.w*wm3[3]
                     + hB.x*wm3[4]+hB.y*wm3[5]+hB.z*wm3[6]+hB.w*wm3[7];
            const float g0 = bflo(hp.x), g1x = bfhi(hp.x);
            const float g1y = bflo(hp.y), g1z = bfhi(hp.y);
            acc0a += w1 * g0 * ea.x;
            acc0b += w4 * (g1x * ea.y + g1y * ea.z + g1z * ea.w);
            const float wg = w2 * g0, w3a = w3 * ea.x;
            s1a[0] += wg * ea.y;  s1a[1] += wg * ea.z;  s1a[2] += wg * ea.w;
            s1b[0] += w3a * g1x;  s1b[1] += w3a * g1y;  s1b[2] += w3a * g1z;

            if (e1 == -1) break;
            ea = eaN; hA = hAN; hB = hBN; hp = hpN;
            e1 = e2; v1 = v2;
        }
    }

    const float f = INV_E * INV_N * INV2;
    u16* a1p = &A1[(size_t)n * 192];
    a1p[lane]      = f2bf(acc0a * f);
    a1p[64 + lane] = f2bf(acc0b * f * INV_SQRT3);
    #pragma unroll
    for (int d = 0; d < 3; ++d) {
        u16* a2p = &A2g[((size_t)n * 3 + d) * 128];
        a2p[lane]      = f2bf(s1a[d] * f);
        a2p[64 + lane] = f2bf(s1b[d] * f);
    }
}

// ---------------------------------------------------------------------------
// Fused post-GEMM + epilogue v7: preload-everything restructure.
//   All global loads (A frags, B frags, x1p words, x rows, attrs) issued
//   up front into statically-indexed registers -> ~50 VMEM in flight per
//   wave instead of ~1-2 (v6 was latency-serialized at VGPR_Count=64).
//   sat LDS staging + first barrier removed (attrs read per-lane, L1-hot).
//   __launch_bounds__(256,5): grid supplies 4.88 blocks/CU; cap VGPR ~408.
// ---------------------------------------------------------------------------
__global__ __launch_bounds__(256, 5) void k_gemm_fused(
    const u16* __restrict__ A1, const u16* __restrict__ A2g,
    const u16* __restrict__ x1p,
    const u16* __restrict__ Bt1m, const u16* __restrict__ Bt1z,
    const u16* __restrict__ Bt2,
    const float* __restrict__ attrs, const float* __restrict__ x,
    float* __restrict__ out)
{
    const int lane = threadIdx.x & 63;
    const int wave = threadIdx.x >> 6;
    const int quad = lane >> 4, l16 = lane & 15;
    const int n0 = blockIdx.x * 16;

    __shared__ float st0[16][132];
    __shared__ float st1[48][68];

    const u16* a0p  = A1  + (size_t)(n0 + l16) * 192 + quad * 8;
    const u16* a1p  = A2g + (size_t)(3 * n0 + l16) * 128 + quad * 8;
    const u16* b0p  = Bt1m + (size_t)(wave * 16 + l16) * 128 + quad * 8;
    const u16* b1p  = Bt1m + (size_t)((wave + 4) * 16 + l16) * 128 + quad * 8;
    const u16* bz0p = Bt1z + (size_t)(wave * 16 + l16) * 64 + quad * 8;
    const u16* bz1p = Bt1z + (size_t)((wave + 4) * 16 + l16) * 64 + quad * 8;
    const u16* b2p  = Bt2 + (size_t)(wave * 16 + l16) * 384 + quad * 8;
    const u16* xq0  = x1p + (size_t)(3 * n0 + l16) * 64 + quad * 2;
    const float4* at4 = (const float4*)attrs;

    // ---- Phase 1: issue ALL global loads into registers ----
    // A-side first (HBM-cold, longest latency), then B (L2-hot), then x rows.
    bf16x8 A2f[3][4];
    #pragma unroll
    for (int rt = 0; rt < 3; ++rt)
        #pragma unroll
        for (int kt = 0; kt < 4; ++kt)
            A2f[rt][kt] = *(const bf16x8*)(a1p + rt * 16 * 128 + kt * 32);

    bf16x8 A0f[6];
    #pragma unroll
    for (int kt = 0; kt < 6; ++kt)
        A0f[kt] = *(const bf16x8*)(a0p + kt * 32);

    u32 XQ[3][8];
    #pragma unroll
    for (int rt = 0; rt < 3; ++rt)
        #pragma unroll
        for (int kt = 0; kt < 8; ++kt)
            XQ[rt][kt] = *(const u32*)(xq0 + rt * 16 * 64 + kt * 8);

    bf16x8 B2m[4];
    #pragma unroll
    for (int kt = 0; kt < 4; ++kt)
        B2m[kt] = *(const bf16x8*)(b2p + kt * 32);
    bf16x8 B2s[8];
    #pragma unroll
    for (int kt = 0; kt < 8; ++kt)
        B2s[kt] = *(const bf16x8*)(b2p + 128 + kt * 32);
    bf16x8 B0f[4], B1f[4];
    #pragma unroll
    for (int kt = 0; kt < 4; ++kt) {
        B0f[kt] = *(const bf16x8*)(b0p + kt * 32);
        B1f[kt] = *(const bf16x8*)(b1p + kt * 32);
    }
    bf16x8 C0f[2][4], C1f[2][4];
    #pragma unroll
    for (int kt = 0; kt < 2; ++kt)
        #pragma unroll
        for (int z = 0; z < 4; ++z) {
            C0f[kt][z] = *(const bf16x8*)(bz0p + z * 8192 + kt * 32);
            C1f[kt][z] = *(const bf16x8*)(bz1p + z * 8192 + kt * 32);
        }

    float xv[16];
    #pragma unroll
    for (int t = 0; t < 16; ++t)
        xv[t] = x[(size_t)(n0 + t) * 256 + threadIdx.x];

    // per-r attrs (for z-combine; nodes n0+quad*4+r), L1-broadcast
    float4 af4[4];
    #pragma unroll
    for (int r = 0; r < 4; ++r)
        af4[r] = at4[n0 + quad * 4 + r];

    // per-lane attr*INV_SC for the 3 t1 row-tiles (row = 3*n0 + rt*16 + l16)
    float4 atv[3];
    #pragma unroll
    for (int rt = 0; rt < 3; ++rt) {
        const int ro = rt * 16 + l16;            // 0..47
        const int nn = (ro * 21846) >> 16;       // ro/3
        float4 v = at4[n0 + nn];
        atv[rt].x = v.x * INV_SC; atv[rt].y = v.y * INV_SC;
        atv[rt].z = v.z * INV_SC; atv[rt].w = v.w * INV_SC;
    }

    // ---- Phase 2: MFMAs (consume in load order) ----
    f32x4 m0 = {}, m1 = {};
    f32x4 mt[3] = {};
    f32x4 z0[4] = {}, z1[4] = {};

    // t1 main: gathered 128 cols of A2g
    #pragma unroll
    for (int kt = 0; kt < 4; ++kt) {
        mt[0] = MFMA(A2f[0][kt], B2m[kt], mt[0]);
        mt[1] = MFMA(A2f[1][kt], B2m[kt], mt[1]);
        mt[2] = MFMA(A2f[2][kt], B2m[kt], mt[2]);
    }
    // t0 main
    #pragma unroll
    for (int kt = 0; kt < 4; ++kt) {
        m0 = MFMA(A0f[kt], B0f[kt], m0);
        m1 = MFMA(A0f[kt], B1f[kt], m1);
    }
    // t0 sc: x0 @ Wsc0_z (z-sliced B, combined with attr in epilogue)
    #pragma unroll
    for (int kt = 0; kt < 2; ++kt)
        #pragma unroll
        for (int z = 0; z < 4; ++z) {
            z0[z] = MFMA(A0f[4 + kt], C0f[kt][z], z0[z]);
            z1[z] = MFMA(A0f[4 + kt], C1f[kt][z], z1[z]);
        }
    // t1 sc: A-fragment = bf16(x1[u]*attr[z]*INV_SC) computed on the fly
    #pragma unroll
    for (int kt = 0; kt < 8; ++kt) {
        #pragma unroll
        for (int rt = 0; rt < 3; ++rt) {
            const u32 xp = XQ[rt][kt];
            const float xa = bflo(xp), xb = bfhi(xp);
            const float a0 = atv[rt].x, a1 = atv[rt].y,
                        a2 = atv[rt].z, a3 = atv[rt].w;
            bf16x8 af;
            af[0] = (short)f2bf(xa * a0); af[1] = (short)f2bf(xa * a1);
            af[2] = (short)f2bf(xa * a2); af[3] = (short)f2bf(xa * a3);
            af[4] = (short)f2bf(xb * a0); af[5] = (short)f2bf(xb * a1);
            af[6] = (short)f2bf(xb * a2); af[7] = (short)f2bf(xb * a3);
            mt[rt] = MFMA(af, B2s[kt], mt[rt]);
        }
    }

    // ---- Phase 3: combine to LDS, barrier, epilogue from registers ----
    #pragma unroll
    for (int r = 0; r < 4; ++r) {
        const int r0 = quad * 4 + r;
        const float ta = af4[r].x, tb = af4[r].y,
                    tc = af4[r].z, td = af4[r].w;
        st0[r0][wave * 16 + l16] =
            m0[r] + ta * z0[0][r] + tb * z0[1][r] + tc * z0[2][r] + td * z0[3][r];
        st0[r0][(wave + 4) * 16 + l16] =
            m1[r] + ta * z1[0][r] + tb * z1[1][r] + tc * z1[2][r] + td * z1[3][r];
        st1[r0][wave * 16 + l16]      = mt[0][r];
        st1[16 + r0][wave * 16 + l16] = mt[1][r];
        st1[32 + r0][wave * 16 + l16] = mt[2][r];
    }
    __syncthreads();

    const int c = threadIdx.x;
    #pragma unroll
    for (int t = 0; t < 16; ++t) {
        float o;
        if (c < 64) {
            o = xv[t] + silu(st0[t][c]);
        } else {
            int r = c - 64;
            int w = (r * 21846) >> 16;      // r/3
            int d = r - w * 3;
            o = xv[t] + silu(st0[t][64 + w]) * st1[t * 3 + d][w];
        }
        out[(size_t)(n0 + t) * 256 + c] = o;
    }
}

extern "C" void kernel_launch(void* const* d_in, const int* in_sizes, int n_in,
                              void* d_out, int out_size, void* d_ws, size_t ws_size,
                              hipStream_t stream) {
    const float* node_feats = (const float*)d_in[0];
    const float* node_attrs = (const float*)d_in[1];
    const float* edge_attrs = (const float*)d_in[2];
    const float* edge_emb   = (const float*)d_in[3];
    const float* W_lin1_0   = (const float*)d_in[4];
    const float* W_lin1_1   = (const float*)d_in[5];
    const float* W_mlp1     = (const float*)d_in[6];
    const float* W_mlp2     = (const float*)d_in[7];
    const float* W_lin2_0   = (const float*)d_in[8];
    const float* W_lin2_1   = (const float*)d_in[9];
    const float* W_sc0      = (const float*)d_in[10];
    const float* W_sc1      = (const float*)d_in[11];
    const int*   edge_index = (const int*)d_in[12];
    float* out = (float*)d_out;

    char* p = (char*)d_ws;
    float* hid = (float*)p;                 p += (size_t)E * 8 * 4;
    u16* hc    = (u16*)p;                   p += (size_t)N * 256 * 2;
    u16* A1    = (u16*)p;                   p += (size_t)N * 192 * 2;
    u16* A2g   = (u16*)p;                   p += (size_t)N * 3 * 128 * 2;
    u16* x1p   = (u16*)p;                   p += (size_t)N * 3 * 64 * 2;
    u16* Bt1m  = (u16*)p;                   p += 16384 * 2;
    u16* Bt1z  = (u16*)p;                   p += 32768 * 2;
    u16* Bt2   = (u16*)p;                   p += 24576 * 2;
    u16* W0b   = (u16*)p;                   p += 4096 * 2;
    u16* W1b   = (u16*)p;                   p += 4096 * 2;
    int* head  = (int*)p;                   p += N * 4;
    int2* nl   = (int2*)p;                  p += (size_t)E * 8;

    hipMemsetAsync(head, 0xFF, N * sizeof(int), stream);

    k_front<<<PREP_B + WCONV_B + HID_B + LIST_B, 256, 0, stream>>>(
        node_feats, edge_emb, edge_index,
        W_lin2_0, W_sc0, W_lin2_1, W_sc1, W_lin1_0, W_lin1_1, W_mlp1,
        A1, x1p, Bt1m, Bt1z, Bt2, W0b, W1b, hid, head, nl);
    k_hgemm<<<1250, 256, 0, stream>>>(A1, x1p, W0b, W1b, hc);
    k_gather<<<N / 4, 256, 0, stream>>>(head, nl, edge_attrs, hid,
                                        (const u32*)hc, W_mlp2, A1, A2g);
    k_gemm_fused<<<1250, 256, 0, stream>>>(A1, A2g, x1p, Bt1m, Bt1z, Bt2,
                                           node_attrs, node_feats, out);
}